// Round 14
// baseline (1016.319 us; speedup 1.0000x reference)
//
#include <hip/hip_runtime.h>

namespace {
constexpr int kB = 512;
constexpr int kT = 200;
constexpr int kI = 784;
constexpr int kH = 128;
constexpr int kO = 10;
constexpr int kM = kB * kT;  // 102400 rows
constexpr float kBeta = 0.9f;
constexpr float kThr = 1.0f;
}  // namespace

// ---------------------------------------------------------------------------
// C[M][128] 64x64 tile = A[M][K] . W[128][K]^T (+bias). REGISTER-ONLY:
// no LDS, no barriers. One wave per block, 8x8 per-thread tile.
//
// r8-r13 diagnosis: every LDS-staged shape pinned at ~60% VALUBusy because
// the shared LDS pipe (4 ds_read_b128/kk/wave ~ 48cy vs 128 VALU cy across
// 4 SIMDs) is structurally oversubscribed. Here both operands stream from
// global as float4-along-k: a-load instrs touch 8 distinct 16B segments
// (coalescer dedups the 8-lane broadcast), b-loads likewise; W is
// L2-resident, A has 4-group L1 line reuse. Explicit depth-1 register
// double-buffer (named sets, unroll-by-2 — r6-proven allocation-safe;
// NG even for K=784 and K=128). ~16 loads in flight under 512cy FMA.
// Per-output k-order: ascending full K, bias added in epilogue — exactly
// the r1-r6 proven-bitwise order.
// ---------------------------------------------------------------------------
template <int K>
__global__ __launch_bounds__(64, 2) void gemm_reg64(
    const float* __restrict__ A, const float* __restrict__ W,
    const float* __restrict__ bias, float* __restrict__ C) {
  constexpr int NG = K / 4;  // 4-k groups; 196 / 32 — both even
  const int tid = threadIdx.x;
  const int tn = tid & 7;    // n-group 0..7
  const int tm = tid >> 3;   // m-group 0..7
  const int mtile = blockIdx.x >> 1;
  const int n0 = (blockIdx.x & 1) * 64;  // n-halves adjacent -> L2 reuse of A
  const int row0 = mtile * 64;

  const float* A0 = A + (size_t)(row0 + tm * 4) * K;
  const float* A1 = A + (size_t)(row0 + 32 + tm * 4) * K;
  const float* W0 = W + (size_t)(n0 + tn * 4) * K;
  const float* W1 = W + (size_t)(n0 + 32 + tn * 4) * K;

  float acc[8][8];
#pragma unroll
  for (int i = 0; i < 8; ++i)
#pragma unroll
    for (int j = 0; j < 8; ++j) acc[i][j] = 0.0f;

  float4 a0[8], b0[8], a1[8], b1[8];

#define LOADG(aa, bb, g)                                                     \
  {                                                                          \
    const int k_ = (g) * 4;                                                  \
    _Pragma("unroll") for (int i = 0; i < 4; ++i) {                          \
      aa[i] = *reinterpret_cast<const float4*>(&A0[(size_t)i * K + k_]);     \
      aa[i + 4] = *reinterpret_cast<const float4*>(&A1[(size_t)i * K + k_]); \
      bb[i] = *reinterpret_cast<const float4*>(&W0[(size_t)i * K + k_]);     \
      bb[i + 4] = *reinterpret_cast<const float4*>(&W1[(size_t)i * K + k_]); \
    }                                                                        \
  }

// Per output (i,j): adds in q-order x,y,z,w = ascending k within the group;
// groups ascend -> full ascending-k accumulation per output (bitwise-stable).
#define COMPG(aa, bb)                                                        \
  {                                                                          \
    _Pragma("unroll") for (int i = 0; i < 8; ++i)                            \
    _Pragma("unroll") for (int j = 0; j < 8; ++j) {                          \
      acc[i][j] = fmaf(aa[i].x, bb[j].x, acc[i][j]);                         \
      acc[i][j] = fmaf(aa[i].y, bb[j].y, acc[i][j]);                         \
      acc[i][j] = fmaf(aa[i].z, bb[j].z, acc[i][j]);                         \
      acc[i][j] = fmaf(aa[i].w, bb[j].w, acc[i][j]);                         \
    }                                                                        \
  }

  LOADG(a0, b0, 0);
  for (int g = 0; g < NG; g += 2) {
    LOADG(a1, b1, g + 1);      // in flight under COMPG(a0,b0)
    COMPG(a0, b0);
    if (g + 2 < NG) LOADG(a0, b0, g + 2);  // in flight under COMPG(a1,b1)
    COMPG(a1, b1);
  }
#undef LOADG
#undef COMPG

#pragma unroll
  for (int i = 0; i < 8; ++i) {
    const int m = (i < 4) ? (tm * 4 + i) : (32 + tm * 4 + (i - 4));
    const size_t r = (size_t)(row0 + m);
#pragma unroll
    for (int jh = 0; jh < 2; ++jh) {
      const int n = n0 + jh * 32 + tn * 4;
      float4 v;
      v.x = acc[i][jh * 4 + 0];
      v.y = acc[i][jh * 4 + 1];
      v.z = acc[i][jh * 4 + 2];
      v.w = acc[i][jh * 4 + 3];
      if (bias != nullptr) {
        v.x += bias[n + 0];
        v.y += bias[n + 1];
        v.z += bias[n + 2];
        v.w += bias[n + 3];
      }
      *reinterpret_cast<float4*>(&C[r * 128 + n]) = v;
    }
  }
}

#define LIF_STEP(mm, ss, curexpr)                                      \
  {                                                                    \
    const float cur_ = (curexpr);                                      \
    mm = __fsub_rn(__fadd_rn(__fmul_rn(kBeta, mm), cur_), ss);         \
    ss = (mm > kThr) ? 1.0f : 0.0f;                                    \
  }

// ---------------------------------------------------------------------------
// In-place LIF scan over [B,T,128] (bias already applied by the GEMM).
// float2 chains + depth-4 load pipeline (r12-proven, absmax 0.0).
// ---------------------------------------------------------------------------
__global__ __launch_bounds__(128) void lif_scan_h(float* __restrict__ buf) {
  const int g = blockIdx.x * 128 + threadIdx.x;  // 0..32767
  const int b = g >> 6;
  const int h2 = (g & 63) * 2;
  const size_t base = (size_t)b * kT * 128 + h2;
#define LD(t) (*reinterpret_cast<const float2*>(&buf[base + (size_t)(t)*128]))
  float2 cA = LD(0), cB = LD(1), cC = LD(2), cD = LD(3);
  float m0 = 0.f, m1 = 0.f, s0 = 0.f, s1 = 0.f;
  for (int t = 0; t < kT; t += 2) {
    const int pa = (t + 4 < kT) ? t + 4 : kT - 1;
    const int pb = (t + 5 < kT) ? t + 5 : kT - 1;
    const float2 nA = LD(pa), nB = LD(pb);
    LIF_STEP(m0, s0, cA.x);
    LIF_STEP(m1, s1, cA.y);
    *reinterpret_cast<float2*>(&buf[base + (size_t)t * 128]) =
        make_float2(s0, s1);
    LIF_STEP(m0, s0, cB.x);
    LIF_STEP(m1, s1, cB.y);
    *reinterpret_cast<float2*>(&buf[base + (size_t)(t + 1) * 128]) =
        make_float2(s0, s1);
    cA = cC; cB = cD; cC = nA; cD = nB;
  }
#undef LD
}

// ---------------------------------------------------------------------------
// GEMM3: cur3[M][10] = s2[M][128] . W3[10][128]^T + b3. (unchanged)
// ---------------------------------------------------------------------------
__global__ __launch_bounds__(320) void gemm3_n10(
    const float* __restrict__ A, const float* __restrict__ W3,
    const float* __restrict__ b3, float* __restrict__ C) {
  __shared__ float Ss[64][132];
  __shared__ float Ws[10][132];
  __shared__ float bs[10];
  const int tid = threadIdx.x;
  const size_t row0 = (size_t)blockIdx.x * 64;

  {
    const int r = tid >> 5;
    const int c4 = (tid & 31) * 4;
    const float4 v = *reinterpret_cast<const float4*>(&W3[r * 128 + c4]);
    Ws[r][c4 + 0] = v.x;
    Ws[r][c4 + 1] = v.y;
    Ws[r][c4 + 2] = v.z;
    Ws[r][c4 + 3] = v.w;
    if (tid < 10) bs[tid] = b3[tid];
  }
  for (int fi = tid; fi < 2048; fi += 320) {
    const int r = fi >> 5;
    const int c4 = (fi & 31) * 4;
    const float4 v =
        *reinterpret_cast<const float4*>(&A[(row0 + r) * 128 + c4]);
    Ss[r][c4 + 0] = v.x;
    Ss[r][c4 + 1] = v.y;
    Ss[r][c4 + 2] = v.z;
    Ss[r][c4 + 3] = v.w;
  }
  __syncthreads();

#pragma unroll
  for (int l = 0; l < 2; ++l) {
    const int idx = tid + l * 320;
    const int r = idx / 10;
    const int o = idx - r * 10;
    float acc = bs[o];
#pragma unroll
    for (int k = 0; k < 128; k += 4) {
      const float4 a = *reinterpret_cast<const float4*>(&Ss[r][k]);
      const float4 w = *reinterpret_cast<const float4*>(&Ws[o][k]);
      acc = fmaf(a.x, w.x, acc);
      acc = fmaf(a.y, w.y, acc);
      acc = fmaf(a.z, w.z, acc);
      acc = fmaf(a.w, w.w, acc);
    }
    C[(row0 + r) * 10 + o] = acc;
  }
}

// ---------------------------------------------------------------------------
// Output LIF scan -> out[t][b][o]. (unchanged)
// ---------------------------------------------------------------------------
__global__ __launch_bounds__(256) void lif_scan_out(
    const float* __restrict__ cur3, float* __restrict__ out) {
  const int g = blockIdx.x * 256 + threadIdx.x;  // 0..5119
  if (g >= kB * kO) return;
  const int b = g / kO;
  const int o = g - b * kO;
  float m = 0.0f, s = 0.0f;
#pragma unroll 4
  for (int t = 0; t < kT; ++t) {
    const float c = cur3[((size_t)b * kT + t) * kO + o];
    m = __fsub_rn(__fadd_rn(__fmul_rn(kBeta, m), c), s);
    s = (m > kThr) ? 1.0f : 0.0f;
    out[(size_t)t * (kB * kO) + g] = s;
  }
}

extern "C" void kernel_launch(void* const* d_in, const int* in_sizes, int n_in,
                              void* d_out, int out_size, void* d_ws,
                              size_t ws_size, hipStream_t stream) {
  (void)in_sizes;
  (void)n_in;
  (void)out_size;
  (void)ws_size;
  const float* x = (const float*)d_in[0];    // [B,T,784]
  const float* W1 = (const float*)d_in[1];   // [128,784]
  const float* b1 = (const float*)d_in[2];   // [128]
  const float* W2 = (const float*)d_in[3];   // [128,128]
  const float* b2 = (const float*)d_in[4];   // [128]
  const float* W3 = (const float*)d_in[5];   // [10,128]
  const float* b3 = (const float*)d_in[6];   // [10]
  float* out = (float*)d_out;                // [T,B,10]

  const size_t bufElems = (size_t)kM * kH;   // 52.4 MB each
  float* P0 = (float*)d_ws;                  // cur1 -> s1 -> cur3
  float* P1 = P0 + bufElems;                 // cur2 -> s2

  // Layer 1: full-K register GEMM, 3200 one-wave blocks, bias fused.
  gemm_reg64<kI><<<2 * (kM / 64), 64, 0, stream>>>(x, W1, b1, P0);
  lif_scan_h<<<256, 128, 0, stream>>>(P0);
  // Layer 2
  gemm_reg64<kH><<<2 * (kM / 64), 64, 0, stream>>>(P0, W2, b2, P1);
  lif_scan_h<<<256, 128, 0, stream>>>(P1);
  // Layer 3: cur3 -> P0 (s1 dead).
  gemm3_n10<<<kM / 64, 320, 0, stream>>>(P1, W3, b3, P0);
  lif_scan_out<<<(kB * kO + 255) / 256, 256, 0, stream>>>(P0, out);
}

// Round 15
// 409.150 us; speedup vs baseline: 2.4840x; 2.4840x over previous
//
#include <hip/hip_runtime.h>

namespace {
constexpr int kB = 512;
constexpr int kT = 200;
constexpr int kI = 784;
constexpr int kH = 128;
constexpr int kO = 10;
constexpr int kM = kB * kT;  // 102400 rows
constexpr float kBeta = 0.9f;
constexpr float kThr = 1.0f;
constexpr int kSplitK0 = 400;  // 784 = 400 + 384 (both %16==0)
}  // namespace

// ---------------------------------------------------------------------------
// Transpose W[N][K] -> WT[K][N]. 16x16 LDS tile. Proven r10/r12.
// ---------------------------------------------------------------------------
__global__ __launch_bounds__(256) void transposeW(const float* __restrict__ W,
                                                  float* __restrict__ WT,
                                                  int N, int K) {
  __shared__ float t[16][17];
  const int k0 = blockIdx.x * 16, n0 = blockIdx.y * 16;
  const int tx = threadIdx.x & 15, ty = threadIdx.x >> 4;
  t[ty][tx] = W[(size_t)(n0 + ty) * K + k0 + tx];
  __syncthreads();
  WT[(size_t)(k0 + ty) * N + n0 + tx] = t[tx][ty];
}

// ---------------------------------------------------------------------------
// Sub-stage: one 16-k tile into LDS rows [kloc, kloc+16). Geometry is
// r12's gemm64bt staging verbatim (6 global loads, 8+4 LDS writes).
// ---------------------------------------------------------------------------
__device__ __forceinline__ void stage16(float (&As)[32][68],
                                        float (&Bs)[32][132],
                                        const float* __restrict__ aptr,
                                        const float* __restrict__ btptr,
                                        int ar0, int ac4, int sbk, int sbn4,
                                        int kloc, int kglob, int KS) {
  const float4 va0 = *reinterpret_cast<const float4*>(aptr + kglob);
  const float4 va1 =
      *reinterpret_cast<const float4*>(aptr + (size_t)32 * KS + kglob);
  const int r0 = ar0, r1 = ar0 + 32;
  As[kloc + ac4 + 0][r0] = va0.x; As[kloc + ac4 + 1][r0] = va0.y;
  As[kloc + ac4 + 2][r0] = va0.z; As[kloc + ac4 + 3][r0] = va0.w;
  As[kloc + ac4 + 0][r1] = va1.x; As[kloc + ac4 + 1][r1] = va1.y;
  As[kloc + ac4 + 2][r1] = va1.z; As[kloc + ac4 + 3][r1] = va1.w;
#pragma unroll
  for (int l = 0; l < 4; ++l) {
    const float4 vb = *reinterpret_cast<const float4*>(
        btptr + (size_t)(kglob + l * 4) * 128);
    *reinterpret_cast<float4*>(&Bs[kloc + sbk + l * 4][sbn4]) = vb;
  }
}

// Sub-compute: 16 kk from LDS rows [kloc, kloc+16). r12's inner loop verbatim.
__device__ __forceinline__ void comp16(const float (&As)[32][68],
                                       const float (&Bs)[32][132], int kloc,
                                       int ty4, int tx4, float (&acc)[8][8]) {
#pragma unroll
  for (int kk = 0; kk < 16; ++kk) {
    float a[8], b[8];
    *reinterpret_cast<float4*>(&a[0]) =
        *reinterpret_cast<const float4*>(&As[kloc + kk][ty4]);
    *reinterpret_cast<float4*>(&a[4]) =
        *reinterpret_cast<const float4*>(&As[kloc + kk][32 + ty4]);
    *reinterpret_cast<float4*>(&b[0]) =
        *reinterpret_cast<const float4*>(&Bs[kloc + kk][tx4]);
    *reinterpret_cast<float4*>(&b[4]) =
        *reinterpret_cast<const float4*>(&Bs[kloc + kk][64 + tx4]);
#pragma unroll
    for (int i = 0; i < 8; ++i)
#pragma unroll
      for (int j = 0; j < 8; ++j) acc[i][j] = fmaf(a[i], b[j], acc[i][j]);
  }
}

// ---------------------------------------------------------------------------
// C[M][128] = A[M][K-slice] . BT[K-slice][128] (+ bias); BT = W^T (k-major).
// r12's proven 64x128 / 128-thread / 8x8-tile kernel with ONE change:
// BK=32 — two 16-k sub-stages per barrier pair (12 loads issued back-to-back,
// no barrier between) -> one ~600cy latency exposure per 4096cy of FMA
// instead of per 2048cy. LDS 25.6KB single-buffered -> 6 blocks/CU (12
// waves), same as r12. FMA order per output: ascending k -> bitwise-identical.
// K-slice = npairs*32 + (optional) 16-tail.
// ---------------------------------------------------------------------------
template <int KSTRIDE, int SPLIT>
__global__ __launch_bounds__(128, 4) void gemm64bt(
    const float* __restrict__ A, const float* __restrict__ BT,
    const float* __restrict__ bias, float* __restrict__ C, size_t coff) {
  constexpr int BM = 64;
  __shared__ float As[32][68];
  __shared__ float Bs[32][132];
  const int tid = threadIdx.x;
  const int tx4 = (tid & 15) * 4;
  const int ty4 = (tid >> 4) * 4;
  int tile, kbeg, n16;
  if (SPLIT) {
    tile = blockIdx.x >> 1;
    const int half = blockIdx.x & 1;
    kbeg = half ? kSplitK0 : 0;
    n16 = (half ? (KSTRIDE - kSplitK0) : kSplitK0) / 16;
    if (half) C += coff;
  } else {
    tile = blockIdx.x;
    kbeg = 0;
    n16 = KSTRIDE / 16;
  }
  const int row0 = tile * BM;
  const int npairs = n16 >> 1;
  const int tail = n16 & 1;

  const int ar0 = tid >> 2;        // 0..31
  const int ac4 = (tid & 3) * 4;
  const int sbk = tid >> 5;        // 0..3
  const int sbn4 = (tid & 31) * 4; // 0..124

  const float* aptr = A + (size_t)(row0 + ar0) * KSTRIDE + kbeg + ac4;
  const float* btptr = BT + (size_t)(kbeg + sbk) * 128 + sbn4;

  float acc[8][8];
#pragma unroll
  for (int i = 0; i < 8; ++i)
#pragma unroll
    for (int j = 0; j < 8; ++j) acc[i][j] = 0.0f;

  for (int p = 0; p < npairs; ++p) {
    const int k0 = p * 32;
    __syncthreads();
    stage16(As, Bs, aptr, btptr, ar0, ac4, sbk, sbn4, 0, k0, KSTRIDE);
    stage16(As, Bs, aptr, btptr, ar0, ac4, sbk, sbn4, 16, k0 + 16, KSTRIDE);
    __syncthreads();
    comp16(As, Bs, 0, ty4, tx4, acc);
    comp16(As, Bs, 16, ty4, tx4, acc);
  }
  if (tail) {
    __syncthreads();
    stage16(As, Bs, aptr, btptr, ar0, ac4, sbk, sbn4, 0, npairs * 32, KSTRIDE);
    __syncthreads();
    comp16(As, Bs, 0, ty4, tx4, acc);
  }

#pragma unroll
  for (int i = 0; i < 8; ++i) {
    const int m = (i < 4) ? (ty4 + i) : (32 + ty4 + (i - 4));
    const size_t r = (size_t)(row0 + m);
#pragma unroll
    for (int jh = 0; jh < 2; ++jh) {
      const int n = jh * 64 + tx4;
      float4 v;
      v.x = acc[i][jh * 4 + 0];
      v.y = acc[i][jh * 4 + 1];
      v.z = acc[i][jh * 4 + 2];
      v.w = acc[i][jh * 4 + 3];
      if (bias != nullptr) {
        v.x += bias[n + 0];
        v.y += bias[n + 1];
        v.z += bias[n + 2];
        v.w += bias[n + 3];
      }
      *reinterpret_cast<float4*>(&C[r * 128 + n]) = v;
    }
  }
}

#define LIF_STEP(mm, ss, curexpr)                                      \
  {                                                                    \
    const float cur_ = (curexpr);                                      \
    mm = __fsub_rn(__fadd_rn(__fmul_rn(kBeta, mm), cur_), ss);         \
    ss = (mm > kThr) ? 1.0f : 0.0f;                                    \
  }

// ---------------------------------------------------------------------------
// Layer-1 LIF scan + combine: cur = (P0+P1)+b1; spikes -> P0. (r12's)
// ---------------------------------------------------------------------------
__global__ __launch_bounds__(128) void lif_scan13(
    float* __restrict__ P0, const float* __restrict__ P1,
    const float* __restrict__ b1) {
  const int g = blockIdx.x * 128 + threadIdx.x;  // 0..32767
  const int b = g >> 6;
  const int h2 = (g & 63) * 2;
  const size_t base = (size_t)b * kT * 128 + h2;
  const float bb0 = b1[h2], bb1 = b1[h2 + 1];
#define LD0(t) (*reinterpret_cast<const float2*>(&P0[base + (size_t)(t)*128]))
#define LD1(t) (*reinterpret_cast<const float2*>(&P1[base + (size_t)(t)*128]))
  float2 cA0 = LD0(0), cA1 = LD1(0), cB0 = LD0(1), cB1 = LD1(1);
  float2 cC0 = LD0(2), cC1 = LD1(2), cD0 = LD0(3), cD1 = LD1(3);
  float m0 = 0.f, m1 = 0.f, s0 = 0.f, s1 = 0.f;
  for (int t = 0; t < kT; t += 2) {
    const int pa = (t + 4 < kT) ? t + 4 : kT - 1;
    const int pb = (t + 5 < kT) ? t + 5 : kT - 1;
    const float2 nA0 = LD0(pa), nA1 = LD1(pa);
    const float2 nB0 = LD0(pb), nB1 = LD1(pb);
    LIF_STEP(m0, s0, __fadd_rn(__fadd_rn(cA0.x, cA1.x), bb0));
    LIF_STEP(m1, s1, __fadd_rn(__fadd_rn(cA0.y, cA1.y), bb1));
    *reinterpret_cast<float2*>(&P0[base + (size_t)t * 128]) =
        make_float2(s0, s1);
    LIF_STEP(m0, s0, __fadd_rn(__fadd_rn(cB0.x, cB1.x), bb0));
    LIF_STEP(m1, s1, __fadd_rn(__fadd_rn(cB0.y, cB1.y), bb1));
    *reinterpret_cast<float2*>(&P0[base + (size_t)(t + 1) * 128]) =
        make_float2(s0, s1);
    cA0 = cC0; cA1 = cC1; cB0 = cD0; cB1 = cD1;
    cC0 = nA0; cC1 = nA1; cD0 = nB0; cD1 = nB1;
  }
#undef LD0
#undef LD1
}

// ---------------------------------------------------------------------------
// Layer-2 LIF scan, in place. (r12's)
// ---------------------------------------------------------------------------
__global__ __launch_bounds__(128) void lif_scan2(float* __restrict__ buf) {
  const int g = blockIdx.x * 128 + threadIdx.x;  // 0..32767
  const int b = g >> 6;
  const int h2 = (g & 63) * 2;
  const size_t base = (size_t)b * kT * 128 + h2;
#define LD(t) (*reinterpret_cast<const float2*>(&buf[base + (size_t)(t)*128]))
  float2 cA = LD(0), cB = LD(1), cC = LD(2), cD = LD(3);
  float m0 = 0.f, m1 = 0.f, s0 = 0.f, s1 = 0.f;
  for (int t = 0; t < kT; t += 2) {
    const int pa = (t + 4 < kT) ? t + 4 : kT - 1;
    const int pb = (t + 5 < kT) ? t + 5 : kT - 1;
    const float2 nA = LD(pa), nB = LD(pb);
    LIF_STEP(m0, s0, cA.x);
    LIF_STEP(m1, s1, cA.y);
    *reinterpret_cast<float2*>(&buf[base + (size_t)t * 128]) =
        make_float2(s0, s1);
    LIF_STEP(m0, s0, cB.x);
    LIF_STEP(m1, s1, cB.y);
    *reinterpret_cast<float2*>(&buf[base + (size_t)(t + 1) * 128]) =
        make_float2(s0, s1);
    cA = cC; cB = cD; cC = nA; cD = nB;
  }
#undef LD
}

// ---------------------------------------------------------------------------
// GEMM3: cur3[M][10] = s2[M][128] . W3[10][128]^T + b3. (unchanged)
// ---------------------------------------------------------------------------
__global__ __launch_bounds__(320) void gemm3_n10(
    const float* __restrict__ A, const float* __restrict__ W3,
    const float* __restrict__ b3, float* __restrict__ C) {
  __shared__ float Ss[64][132];
  __shared__ float Ws[10][132];
  __shared__ float bs[10];
  const int tid = threadIdx.x;
  const size_t row0 = (size_t)blockIdx.x * 64;

  {
    const int r = tid >> 5;
    const int c4 = (tid & 31) * 4;
    const float4 v = *reinterpret_cast<const float4*>(&W3[r * 128 + c4]);
    Ws[r][c4 + 0] = v.x;
    Ws[r][c4 + 1] = v.y;
    Ws[r][c4 + 2] = v.z;
    Ws[r][c4 + 3] = v.w;
    if (tid < 10) bs[tid] = b3[tid];
  }
  for (int fi = tid; fi < 2048; fi += 320) {
    const int r = fi >> 5;
    const int c4 = (fi & 31) * 4;
    const float4 v =
        *reinterpret_cast<const float4*>(&A[(row0 + r) * 128 + c4]);
    Ss[r][c4 + 0] = v.x;
    Ss[r][c4 + 1] = v.y;
    Ss[r][c4 + 2] = v.z;
    Ss[r][c4 + 3] = v.w;
  }
  __syncthreads();

#pragma unroll
  for (int l = 0; l < 2; ++l) {
    const int idx = tid + l * 320;
    const int r = idx / 10;
    const int o = idx - r * 10;
    float acc = bs[o];
#pragma unroll
    for (int k = 0; k < 128; k += 4) {
      const float4 a = *reinterpret_cast<const float4*>(&Ss[r][k]);
      const float4 w = *reinterpret_cast<const float4*>(&Ws[o][k]);
      acc = fmaf(a.x, w.x, acc);
      acc = fmaf(a.y, w.y, acc);
      acc = fmaf(a.z, w.z, acc);
      acc = fmaf(a.w, w.w, acc);
    }
    C[(row0 + r) * 10 + o] = acc;
  }
}

// ---------------------------------------------------------------------------
// Output LIF scan -> out[t][b][o]. (unchanged)
// ---------------------------------------------------------------------------
__global__ __launch_bounds__(256) void lif_scan_out(
    const float* __restrict__ cur3, float* __restrict__ out) {
  const int g = blockIdx.x * 256 + threadIdx.x;  // 0..5119
  if (g >= kB * kO) return;
  const int b = g / kO;
  const int o = g - b * kO;
  float m = 0.0f, s = 0.0f;
#pragma unroll 4
  for (int t = 0; t < kT; ++t) {
    const float c = cur3[((size_t)b * kT + t) * kO + o];
    m = __fsub_rn(__fadd_rn(__fmul_rn(kBeta, m), c), s);
    s = (m > kThr) ? 1.0f : 0.0f;
    out[(size_t)t * (kB * kO) + g] = s;
  }
}

extern "C" void kernel_launch(void* const* d_in, const int* in_sizes, int n_in,
                              void* d_out, int out_size, void* d_ws,
                              size_t ws_size, hipStream_t stream) {
  (void)in_sizes;
  (void)n_in;
  (void)out_size;
  (void)ws_size;
  const float* x = (const float*)d_in[0];    // [B,T,784]
  const float* W1 = (const float*)d_in[1];   // [128,784]
  const float* b1 = (const float*)d_in[2];   // [128]
  const float* W2 = (const float*)d_in[3];   // [128,128]
  const float* b2 = (const float*)d_in[4];   // [128]
  const float* W3 = (const float*)d_in[5];   // [10,128]
  const float* b3 = (const float*)d_in[6];   // [10]
  float* out = (float*)d_out;                // [T,B,10] = 4.1 MB

  const size_t bufElems = (size_t)kM * kH;   // 52.4 MB each
  float* P0 = (float*)d_ws;                  // partial0 -> s1 -> cur3
  float* P1 = P0 + bufElems;                 // partial1 -> cur2 -> s2

  // W1T + W2T (467 KB) stashed at the head of d_out (overwritten at end).
  float* W1T = out;
  float* W2T = W1T + (size_t)kI * kH;

  transposeW<<<dim3(kI / 16, kH / 16), 256, 0, stream>>>(W1, W1T, kH, kI);
  transposeW<<<dim3(kH / 16, kH / 16), 256, 0, stream>>>(W2, W2T, kH, kH);

  // Layer 1: split-K GEMM, 3200 blocks x 128 threads; scan combines.
  gemm64bt<kI, 1><<<2 * (kM / 64), 128, 0, stream>>>(x, W1T, nullptr, P0,
                                                     bufElems);
  lif_scan13<<<256, 128, 0, stream>>>(P0, P1, b1);
  // Layer 2: full-K GEMM, 1600 blocks.
  gemm64bt<kH, 0><<<kM / 64, 128, 0, stream>>>(P0, W2T, b2, P1, 0);
  lif_scan2<<<256, 128, 0, stream>>>(P1);
  // Layer 3: cur3 -> P0 region (s1 dead).
  gemm3_n10<<<kM / 64, 320, 0, stream>>>(P1, W3, b3, P0);
  lif_scan_out<<<(kB * kO + 255) / 256, 256, 0, stream>>>(P0, out);
}